// Round 3
// baseline (64.775 us; speedup 1.0000x reference)
//
#include <hip/hip_runtime.h>

#define BB 4
#define NN 4096
#define DD 128
#define RB 8            // rows per block (2 per wave)

// Kernel 1: per-row projections. One wave per row; lane l covers dims l, l+64.
// Writes si[row] = x[row]·a1 and e12[row] = {exp(sj), exp(0.2*sj)} where
// sj = x[row]·a2. (exp factorization: leaky breaks into two exp products.)
__global__ __launch_bounds__(256) void score_kernel(const float* __restrict__ x,
                                                    const float* __restrict__ a,
                                                    float* __restrict__ si,
                                                    float2* __restrict__ e12) {
    int wave = threadIdx.x >> 6;
    int lane = threadIdx.x & 63;
    int row  = blockIdx.x * 4 + wave;   // grid covers B*N rows exactly
    const float* xr = x + (size_t)row * DD;
    float x0 = xr[lane];
    float x1 = xr[lane + 64];
    float d1 = x0 * a[lane]      + x1 * a[lane + 64];
    float d2 = x0 * a[DD + lane] + x1 * a[DD + lane + 64];
    #pragma unroll
    for (int off = 1; off < 64; off <<= 1) {
        d1 += __shfl_xor(d1, off, 64);
        d2 += __shfl_xor(d2, off, 64);
    }
    if (lane == 0) {
        si[row] = d1;
        e12[row] = make_float2(__expf(d2), __expf(0.2f * d2));
    }
}

// Kernel 2: one block per RB output rows. E1/E2 for the whole batch held in
// 128 regs/lane, loaded once. Hot loop per element: cmp + 2 mul + cndmask +
// add — no transcendentals, no leaky. Row max m cancels in normalization so
// mj = log(max E1) (approximate) is fine; A1=exp(si-m), A2=exp(0.2si-m) are
// per-row (3 expf per row). Sign test e>0  <=>  E1j > exp(-si).
__global__ __launch_bounds__(256) void softmax_kernel(const float* __restrict__ si_g,
                                                      const float2* __restrict__ e12_g,
                                                      float* __restrict__ out) {
    __shared__ float red[4];

    const int b    = blockIdx.x >> 9;          // 512 blocks per batch
    const int i0   = (blockIdx.x & 511) * RB;
    const int wave = threadIdx.x >> 6;
    const int lane = threadIdx.x & 63;

    // Load batch's {E1,E2} pairs: lane holds j = g*256 + lane*4 .. +3.
    // ev[2g]   = {E1_j0, E2_j0, E1_j1, E2_j1}
    // ev[2g+1] = {E1_j2, E2_j2, E1_j3, E2_j3}
    const float* eb = (const float*)(e12_g + b * NN);
    float4 ev[32];
    float emax = 0.f;                          // E1 > 0 always
    #pragma unroll
    for (int g = 0; g < 16; ++g) {
        const float* p = eb + (size_t)(g * 256 + lane * 4) * 2;
        ev[2 * g]     = *reinterpret_cast<const float4*>(p);
        ev[2 * g + 1] = *reinterpret_cast<const float4*>(p + 4);
        emax = fmaxf(emax, fmaxf(ev[2 * g].x,     ev[2 * g].z));
        emax = fmaxf(emax, fmaxf(ev[2 * g + 1].x, ev[2 * g + 1].z));
    }
    #pragma unroll
    for (int off = 1; off < 64; off <<= 1)
        emax = fmaxf(emax, __shfl_xor(emax, off, 64));
    if (lane == 0) red[wave] = emax;
    __syncthreads();
    const float Emax = fmaxf(fmaxf(red[0], red[1]), fmaxf(red[2], red[3]));
    const float mj = __logf(Emax);             // ~max_j sj (approx ok: m cancels)

    #pragma unroll
    for (int r = 0; r < RB / 4; ++r) {
        const int i = i0 + wave * (RB / 4) + r;
        const float sival = si_g[b * NN + i];
        const float c = sival + mj;
        const float m = c > 0.f ? c : 0.2f * c;         // row max (approx)
        const float T  = __expf(-sival);                 // sign-test threshold
        const float A1 = __expf(sival - m);
        const float A2 = __expf(0.2f * sival - m);

        float lsum = 0.f;
        #pragma unroll
        for (int g = 0; g < 16; ++g) {
            float4 e0 = ev[2 * g], e1 = ev[2 * g + 1];
            float p0 = (e0.x > T) ? A1 * e0.x : A2 * e0.y;
            float p1 = (e0.z > T) ? A1 * e0.z : A2 * e0.w;
            float p2 = (e1.x > T) ? A1 * e1.x : A2 * e1.y;
            float p3 = (e1.z > T) ? A1 * e1.z : A2 * e1.w;
            lsum += (p0 + p1) + (p2 + p3);
        }
        #pragma unroll
        for (int off = 1; off < 64; off <<= 1)
            lsum += __shfl_xor(lsum, off, 64);
        const float inv = 1.f / lsum;
        const float B1 = A1 * inv;
        const float B2 = A2 * inv;

        float* orow = out + (size_t)(b * NN + i) * NN;
        #pragma unroll
        for (int g = 0; g < 16; ++g) {
            float4 e0 = ev[2 * g], e1 = ev[2 * g + 1];
            float4 v;
            v.x = (e0.x > T) ? B1 * e0.x : B2 * e0.y;
            v.y = (e0.z > T) ? B1 * e0.z : B2 * e0.w;
            v.z = (e1.x > T) ? B1 * e1.x : B2 * e1.y;
            v.w = (e1.z > T) ? B1 * e1.z : B2 * e1.w;
            *reinterpret_cast<float4*>(orow + g * 256 + lane * 4) = v;
        }
    }
}

extern "C" void kernel_launch(void* const* d_in, const int* in_sizes, int n_in,
                              void* d_out, int out_size, void* d_ws, size_t ws_size,
                              hipStream_t stream) {
    const float* x = (const float*)d_in[0];
    const float* a = (const float*)d_in[1];
    float* out = (float*)d_out;
    float* si = (float*)d_ws;                 // B*N floats
    float2* e12 = (float2*)(si + BB * NN);    // B*N float2 (192 KB total, << ws)

    score_kernel<<<(BB * NN) / 4, 256, 0, stream>>>(x, a, si, e12);
    softmax_kernel<<<(BB * NN) / RB, 256, 0, stream>>>(si, e12, out);
}